// Round 1
// baseline (1916.134 us; speedup 1.0000x reference)
//
#include <hip/hip_runtime.h>
#include <hip/hip_bf16.h>
#include <math.h>

#define NNODES 100000
#define NEDGES 1600000
#define EPLUS  (NEDGES + NNODES)   // edges + self loops
#define INF    128
#define HF     64
#define NEG_SLOPE 0.2f

// ---- monotone float<->uint map for atomicMax on floats ----
__device__ __forceinline__ unsigned fmap(float f) {
    unsigned u = __float_as_uint(f);
    return (u & 0x80000000u) ? ~u : (u | 0x80000000u);
}
__device__ __forceinline__ float funmap(unsigned u) {
    return __uint_as_float((u & 0x80000000u) ? (u ^ 0x80000000u) : ~u);
}

// ---- build int32 edge lists with self-loops appended ----
__global__ void k_edges(const int* __restrict__ ei, int* __restrict__ s32, int* __restrict__ d32) {
    int i = blockIdx.x * blockDim.x + threadIdx.x;
    if (i >= EPLUS) return;
    if (i < NEDGES) { s32[i] = ei[i]; d32[i] = ei[NEDGES + i]; }
    else            { s32[i] = i - NEDGES; d32[i] = i - NEDGES; }
}

// ---- H = X @ W ; ls = H@asrc ; ld = H@adst  (wave per node, lane = out feature) ----
template<int IN>
__global__ __launch_bounds__(256) void k_transform(const float* __restrict__ X,
        const float* __restrict__ W, const float* __restrict__ asrc, const float* __restrict__ adst,
        float* __restrict__ H, float* __restrict__ ls, float* __restrict__ ld) {
    __shared__ float Wl[IN * HF];
    for (int i = threadIdx.x; i < IN * HF; i += 256) Wl[i] = W[i];
    __syncthreads();
    const int lane = threadIdx.x & 63;
    const int wave = threadIdx.x >> 6;
    const float as = asrc[lane], ad = adst[lane];
    for (long long n = (long long)blockIdx.x * 4 + wave; n < NNODES; n += (long long)gridDim.x * 4) {
        const float4* xr = (const float4*)(X + n * IN);
        float acc = 0.f;
        #pragma unroll
        for (int k4 = 0; k4 < IN / 4; ++k4) {
            float4 xv = xr[k4];
            acc += xv.x * Wl[(k4 * 4 + 0) * HF + lane];
            acc += xv.y * Wl[(k4 * 4 + 1) * HF + lane];
            acc += xv.z * Wl[(k4 * 4 + 2) * HF + lane];
            acc += xv.w * Wl[(k4 * 4 + 3) * HF + lane];
        }
        H[n * HF + lane] = acc;
        float rs = acc * as, rd = acc * ad;
        #pragma unroll
        for (int o = 32; o; o >>= 1) { rs += __shfl_xor(rs, o); rd += __shfl_xor(rd, o); }
        if (lane == 0) { ls[n] = rs; ld[n] = rd; }
    }
}

// ---- init per-layer state: m=-inf, denom=0, acc=0 ----
__global__ void k_init(unsigned* __restrict__ m, float* __restrict__ denom, float* __restrict__ acc) {
    long long i = (long long)blockIdx.x * blockDim.x + threadIdx.x;
    if (i >= (long long)NNODES * HF) return;
    acc[i] = 0.f;
    if (i < NNODES) { m[i] = 0x007FFFFFu /* fmap(-inf) */; denom[i] = 0.f; }
}

// ---- pass 1: segment max of leaky-relu logits ----
__global__ void k_emax(const int* __restrict__ s32, const int* __restrict__ d32,
                       const float* __restrict__ ls, const float* __restrict__ ld,
                       unsigned* __restrict__ m) {
    int i = blockIdx.x * blockDim.x + threadIdx.x;
    if (i >= EPLUS) return;
    int s = s32[i], d = d32[i];
    float e = ls[s] + ld[d];
    e = e > 0.f ? e : NEG_SLOPE * e;
    atomicMax(&m[d], fmap(e));
}

// ---- pass 2: p=exp(e-m), denom += p, acc[dst] += p*H[src]  (wave per edge) ----
__global__ __launch_bounds__(256) void k_eagg(const int* __restrict__ s32, const int* __restrict__ d32,
        const float* __restrict__ ls, const float* __restrict__ ld,
        const unsigned* __restrict__ m, const float* __restrict__ H,
        float* __restrict__ denom, float* __restrict__ acc) {
    long long e = (long long)blockIdx.x * 4 + (threadIdx.x >> 6);
    if (e >= EPLUS) return;
    const int lane = threadIdx.x & 63;
    int s = s32[e], d = d32[e];
    float ev = ls[s] + ld[d];
    ev = ev > 0.f ? ev : NEG_SLOPE * ev;
    float p = __expf(ev - funmap(m[d]));
    if (lane == 0) atomicAdd(&denom[d], p);
    atomicAdd(&acc[(long long)d * HF + lane], p * H[(long long)s * HF + lane]);
}

// ---- finish: X_next = relu(acc/denom + b), in place on acc ----
__global__ void k_finish(const float* __restrict__ denom, const float* __restrict__ b,
                         float* __restrict__ acc) {
    long long i = (long long)blockIdx.x * blockDim.x + threadIdx.x;
    if (i >= (long long)NNODES * HF) return;
    int n = (int)(i >> 6), f = (int)(i & 63);
    float v = acc[i] / (denom[n] + 1e-16f) + b[f];
    acc[i] = v > 0.f ? v : 0.f;
}

// ---- classifier: out = X @ Wc + bc  (wave per node) ----
__global__ __launch_bounds__(256) void k_cls(const float* __restrict__ X, const float* __restrict__ Wc,
        const float* __restrict__ bc, float* __restrict__ out) {
    long long n = (long long)blockIdx.x * 4 + (threadIdx.x >> 6);
    if (n >= NNODES) return;
    const int lane = threadIdx.x & 63;
    float v = X[n * HF + lane];
    float r0 = v * Wc[lane * 2 + 0];
    float r1 = v * Wc[lane * 2 + 1];
    #pragma unroll
    for (int o = 32; o; o >>= 1) { r0 += __shfl_xor(r0, o); r1 += __shfl_xor(r1, o); }
    if (lane == 0) { out[n * 2 + 0] = r0 + bc[0]; out[n * 2 + 1] = r1 + bc[1]; }
}

extern "C" void kernel_launch(void* const* d_in, const int* in_sizes, int n_in,
                              void* d_out, int out_size, void* d_ws, size_t ws_size,
                              hipStream_t stream) {
    const float* x      = (const float*)d_in[0];
    const int*   ei     = (const int*)d_in[1];
    const float* W0     = (const float*)d_in[2];
    const float* asrc0  = (const float*)d_in[3];
    const float* adst0  = (const float*)d_in[4];
    const float* b0     = (const float*)d_in[5];
    const float* Ws     = (const float*)d_in[6];
    const float* asrcs  = (const float*)d_in[7];
    const float* adsts  = (const float*)d_in[8];
    const float* bs     = (const float*)d_in[9];
    const float* Wc     = (const float*)d_in[10];
    const float* bc     = (const float*)d_in[11];
    float* out = (float*)d_out;

    // workspace layout
    float* P    = (float*)d_ws;                    // N*64
    float* Q    = P + (long long)NNODES * HF;      // N*64
    float* Hb   = Q + (long long)NNODES * HF;      // N*64
    float* ls   = Hb + (long long)NNODES * HF;     // N
    float* ld   = ls + NNODES;                     // N
    unsigned* m = (unsigned*)(ld + NNODES);        // N
    float* den  = (float*)(m + NNODES);            // N
    int* s32    = (int*)(den + NNODES);            // EPLUS
    int* d32    = s32 + EPLUS;                     // EPLUS

    const int B = 256;
    const int gEdges = (EPLUS + B - 1) / B;
    const int gNF    = (NNODES * HF + B - 1) / B;
    const int gAgg   = (EPLUS + 3) / 4;
    const int gNode4 = (NNODES + 3) / 4;

    k_edges<<<gEdges, B, 0, stream>>>(ei, s32, d32);

    // ---- layer 0: x(128) -> P ----
    k_transform<INF><<<2048, B, 0, stream>>>(x, W0, asrc0, adst0, Hb, ls, ld);
    k_init<<<gNF, B, 0, stream>>>(m, den, P);
    k_emax<<<gEdges, B, 0, stream>>>(s32, d32, ls, ld, m);
    k_eagg<<<gAgg, B, 0, stream>>>(s32, d32, ls, ld, m, Hb, den, P);
    k_finish<<<gNF, B, 0, stream>>>(den, b0, P);

    // ---- layer 1: P -> Q ----
    k_transform<HF><<<2048, B, 0, stream>>>(P, Ws + 0 * HF * HF, asrcs + 0 * HF, adsts + 0 * HF, Hb, ls, ld);
    k_init<<<gNF, B, 0, stream>>>(m, den, Q);
    k_emax<<<gEdges, B, 0, stream>>>(s32, d32, ls, ld, m);
    k_eagg<<<gAgg, B, 0, stream>>>(s32, d32, ls, ld, m, Hb, den, Q);
    k_finish<<<gNF, B, 0, stream>>>(den, bs + 0 * HF, Q);

    // ---- layer 2: Q -> P ----
    k_transform<HF><<<2048, B, 0, stream>>>(Q, Ws + 1 * HF * HF, asrcs + 1 * HF, adsts + 1 * HF, Hb, ls, ld);
    k_init<<<gNF, B, 0, stream>>>(m, den, P);
    k_emax<<<gEdges, B, 0, stream>>>(s32, d32, ls, ld, m);
    k_eagg<<<gAgg, B, 0, stream>>>(s32, d32, ls, ld, m, Hb, den, P);
    k_finish<<<gNF, B, 0, stream>>>(den, bs + 1 * HF, P);

    // ---- classifier ----
    k_cls<<<gNode4, B, 0, stream>>>(P, Wc, bc, out);
}

// Round 2
// 793.665 us; speedup vs baseline: 2.4143x; 2.4143x over previous
//
#include <hip/hip_runtime.h>
#include <hip/hip_bf16.h>
#include <math.h>

#define NNODES 100000
#define NEDGES 1600000
#define EPLUS  (NEDGES + NNODES)   // edges + self loops
#define INF    128
#define HF     64
#define NEG_SLOPE 0.2f
#define NB1 391                     // ceil(NNODES/256)

// ---- build int32 edge lists with self-loops appended ----
__global__ void k_edges(const int* __restrict__ ei, int* __restrict__ s32, int* __restrict__ d32) {
    int i = blockIdx.x * blockDim.x + threadIdx.x;
    if (i >= EPLUS) return;
    if (i < NEDGES) { s32[i] = ei[i]; d32[i] = ei[NEDGES + i]; }
    else            { s32[i] = i - NEDGES; d32[i] = i - NEDGES; }
}

__global__ void k_zero(int* __restrict__ c) {
    int i = blockIdx.x * blockDim.x + threadIdx.x;
    if (i < NNODES) c[i] = 0;
}

__global__ void k_count(const int* __restrict__ d32, int* __restrict__ cnt) {
    int i = blockIdx.x * blockDim.x + threadIdx.x;
    if (i >= EPLUS) return;
    atomicAdd(&cnt[d32[i]], 1);
}

// ---- 3-kernel exclusive scan of cnt[N] -> roff[N] ----
__global__ __launch_bounds__(256) void k_scan_block(const int* __restrict__ cnt,
        int* __restrict__ roff, int* __restrict__ bsum) {
    __shared__ int sm[256];
    const int t = threadIdx.x;
    int i = blockIdx.x * 256 + t;
    int v = (i < NNODES) ? cnt[i] : 0;
    sm[t] = v; __syncthreads();
    #pragma unroll
    for (int o = 1; o < 256; o <<= 1) {
        int x = (t >= o) ? sm[t - o] : 0; __syncthreads();
        sm[t] += x; __syncthreads();
    }
    if (i < NNODES) roff[i] = sm[t] - v;     // exclusive within block
    if (t == 255) bsum[blockIdx.x] = sm[255];
}

__global__ __launch_bounds__(512) void k_scan_top(const int* __restrict__ bsum, int* __restrict__ boff) {
    __shared__ int sm[512];
    const int t = threadIdx.x;
    int v = (t < NB1) ? bsum[t] : 0;
    sm[t] = v; __syncthreads();
    #pragma unroll
    for (int o = 1; o < 512; o <<= 1) {
        int x = (t >= o) ? sm[t - o] : 0; __syncthreads();
        sm[t] += x; __syncthreads();
    }
    if (t < NB1) boff[t] = sm[t] - v;
}

__global__ __launch_bounds__(256) void k_scan_add(int* __restrict__ roff,
        const int* __restrict__ boff, int* __restrict__ woff) {
    int i = blockIdx.x * 256 + threadIdx.x;
    if (i < NNODES) { int r = roff[i] + boff[blockIdx.x]; roff[i] = r; woff[i] = r; }
    if (i == 0) roff[NNODES] = EPLUS;
}

__global__ void k_scatter(const int* __restrict__ s32, const int* __restrict__ d32,
                          int* __restrict__ woff, int* __restrict__ csr) {
    int i = blockIdx.x * blockDim.x + threadIdx.x;
    if (i >= EPLUS) return;
    int d = d32[i];
    int pos = atomicAdd(&woff[d], 1);
    csr[pos] = s32[i];
}

// ---- H = X @ W ; ls = H@asrc ; ld = H@adst  (wave per node, lane = out feature) ----
// Safe in-place for IN==HF (wave reads its full row before writing it).
template<int IN>
__global__ __launch_bounds__(256) void k_transform(const float* __restrict__ X,
        const float* __restrict__ W, const float* __restrict__ asrc, const float* __restrict__ adst,
        float* __restrict__ H, float* __restrict__ ls, float* __restrict__ ld) {
    __shared__ float Wl[IN * HF];
    for (int i = threadIdx.x; i < IN * HF; i += 256) Wl[i] = W[i];
    __syncthreads();
    const int lane = threadIdx.x & 63;
    const int wave = threadIdx.x >> 6;
    const float as = asrc[lane], ad = adst[lane];
    for (long long n = (long long)blockIdx.x * 4 + wave; n < NNODES; n += (long long)gridDim.x * 4) {
        const float4* xr = (const float4*)(X + n * IN);
        float acc = 0.f;
        #pragma unroll
        for (int k4 = 0; k4 < IN / 4; ++k4) {
            float4 xv = xr[k4];
            acc += xv.x * Wl[(k4 * 4 + 0) * HF + lane];
            acc += xv.y * Wl[(k4 * 4 + 1) * HF + lane];
            acc += xv.z * Wl[(k4 * 4 + 2) * HF + lane];
            acc += xv.w * Wl[(k4 * 4 + 3) * HF + lane];
        }
        H[n * HF + lane] = acc;
        float rs = acc * as, rd = acc * ad;
        #pragma unroll
        for (int o = 32; o; o >>= 1) { rs += __shfl_xor(rs, o); rd += __shfl_xor(rd, o); }
        if (lane == 0) { ls[n] = rs; ld[n] = rd; }
    }
}

// ---- CSR aggregation: wave per dst node, lane = feature, online softmax ----
// out = relu(sum_j alpha_j * H[src_j] + b); optionally fused classifier.
template<int FUSE_CLS>
__global__ __launch_bounds__(256) void k_gat(const int* __restrict__ roff, const int* __restrict__ csr,
        const float* __restrict__ ls, const float* __restrict__ ld, const float* __restrict__ H,
        const float* __restrict__ b, float* __restrict__ outX,
        const float* __restrict__ Wc, const float* __restrict__ bc, float* __restrict__ outC) {
    int n = blockIdx.x * 4 + (threadIdx.x >> 6);
    if (n >= NNODES) return;
    const int lane = threadIdx.x & 63;
    const int r0 = roff[n], r1 = roff[n + 1];
    const float ldv = ld[n];
    float m = -INFINITY, den = 0.f, acc = 0.f;
    for (int base = r0; base < r1; base += 64) {
        const int nb = min(64, r1 - base);
        const bool ok = (base + lane < r1);
        int  sv  = ok ? csr[base + lane] : 0;
        float lv = ok ? ls[sv] : 0.f;
        for (int j = 0; j < nb; ++j) {
            int s   = __shfl(sv, j);
            float e = __shfl(lv, j) + ldv;
            e = e > 0.f ? e : NEG_SLOPE * e;
            float mn    = fmaxf(m, e);
            float scale = __expf(m - mn);     // first iter: exp(-inf)=0
            float p     = __expf(e - mn);
            den = den * scale + p;
            acc = acc * scale + p * H[(long long)s * HF + lane];
            m = mn;
        }
    }
    float v = acc / (den + 1e-16f) + b[lane];
    v = fmaxf(v, 0.f);
    if (!FUSE_CLS) {
        outX[(long long)n * HF + lane] = v;
    } else {
        float a0 = v * Wc[lane * 2 + 0];
        float a1 = v * Wc[lane * 2 + 1];
        #pragma unroll
        for (int o = 32; o; o >>= 1) { a0 += __shfl_xor(a0, o); a1 += __shfl_xor(a1, o); }
        if (lane == 0) { outC[n * 2 + 0] = a0 + bc[0]; outC[n * 2 + 1] = a1 + bc[1]; }
    }
}

extern "C" void kernel_launch(void* const* d_in, const int* in_sizes, int n_in,
                              void* d_out, int out_size, void* d_ws, size_t ws_size,
                              hipStream_t stream) {
    const float* x      = (const float*)d_in[0];
    const int*   ei     = (const int*)d_in[1];
    const float* W0     = (const float*)d_in[2];
    const float* asrc0  = (const float*)d_in[3];
    const float* adst0  = (const float*)d_in[4];
    const float* b0     = (const float*)d_in[5];
    const float* Ws     = (const float*)d_in[6];
    const float* asrcs  = (const float*)d_in[7];
    const float* adsts  = (const float*)d_in[8];
    const float* bs     = (const float*)d_in[9];
    const float* Wc     = (const float*)d_in[10];
    const float* bc     = (const float*)d_in[11];
    float* out = (float*)d_out;

    // workspace layout (~74 MB)
    float* Hb   = (float*)d_ws;                    // N*64
    float* P    = Hb + (long long)NNODES * HF;     // N*64
    float* ls   = P + (long long)NNODES * HF;      // N
    float* ld   = ls + NNODES;                     // N
    int* s32    = (int*)(ld + NNODES);             // EPLUS
    int* d32    = s32 + EPLUS;                     // EPLUS
    int* csr    = d32 + EPLUS;                     // EPLUS
    int* cnt    = csr + EPLUS;                     // N
    int* roff   = cnt + NNODES;                    // N+1
    int* woff   = roff + NNODES + 1;               // N
    int* bsum   = woff + NNODES;                   // NB1
    int* boff   = bsum + NB1;                      // NB1

    const int B = 256;
    const int gEdges = (EPLUS + B - 1) / B;
    const int gNodeB = NB1;
    const int gNode4 = (NNODES + 3) / 4;

    // ---- CSR build (once; reused by all 3 layers) ----
    k_edges<<<gEdges, B, 0, stream>>>(ei, s32, d32);
    k_zero<<<gNodeB, B, 0, stream>>>(cnt);
    k_count<<<gEdges, B, 0, stream>>>(d32, cnt);
    k_scan_block<<<gNodeB, B, 0, stream>>>(cnt, roff, bsum);
    k_scan_top<<<1, 512, 0, stream>>>(bsum, boff);
    k_scan_add<<<gNodeB, B, 0, stream>>>(roff, boff, woff);
    k_scatter<<<gEdges, B, 0, stream>>>(s32, d32, woff, csr);

    // ---- layer 0: x(128) -> Hb(h) -> P(x1) ----
    k_transform<INF><<<2048, B, 0, stream>>>(x, W0, asrc0, adst0, Hb, ls, ld);
    k_gat<0><<<gNode4, B, 0, stream>>>(roff, csr, ls, ld, Hb, b0, P, nullptr, nullptr, nullptr);

    // ---- layer 1: P -> P(h, in-place) -> Hb(x2) ----
    k_transform<HF><<<2048, B, 0, stream>>>(P, Ws + 0 * HF * HF, asrcs + 0 * HF, adsts + 0 * HF, P, ls, ld);
    k_gat<0><<<gNode4, B, 0, stream>>>(roff, csr, ls, ld, P, bs + 0 * HF, Hb, nullptr, nullptr, nullptr);

    // ---- layer 2: Hb -> Hb(h, in-place) -> fused classifier -> out ----
    k_transform<HF><<<2048, B, 0, stream>>>(Hb, Ws + 1 * HF * HF, asrcs + 1 * HF, adsts + 1 * HF, Hb, ls, ld);
    k_gat<1><<<gNode4, B, 0, stream>>>(roff, csr, ls, ld, Hb, bs + 1 * HF, nullptr, Wc, bc, out);
}